// Round 10
// baseline (336.131 us; speedup 1.0000x reference)
//
#include <hip/hip_runtime.h>

#define LL 96
#define TT 24
#define HH 64
#define CC 8
#define GG 256   // 4*H
#define BT 8     // batches per block
#define NB 512   // 4096/BT

typedef unsigned short u16t;
typedef unsigned int   u32t;
typedef __attribute__((ext_vector_type(8))) short bf16x8;
typedef __attribute__((ext_vector_type(4))) float f32x4;

__device__ __forceinline__ float b2f(u16t u){ union{u32t i; float f;} v; v.i=((u32t)u)<<16; return v.f; }
__device__ __forceinline__ float lo2f(u32t p){ union{u32t i; float f;} v; v.i=p<<16; return v.f; }
__device__ __forceinline__ float hi2f(u32t p){ union{u32t i; float f;} v; v.i=p&0xffff0000u; return v.f; }
__device__ __forceinline__ u16t f2b(float f){ union{float f; u32t i;} v; v.f=f; u32t l=(v.i>>16)&1u; v.i+=0x7fffu+l; return (u16t)(v.i>>16); }
__device__ __forceinline__ float rcpf(float x){ return __builtin_amdgcn_rcpf(x); }
__device__ __forceinline__ float sigm(float x){ return rcpf(1.f + __expf(-x)); }
__device__ __forceinline__ float tanh2(float x){ return 1.f - 2.f*rcpf(__expf(2.f*x) + 1.f); }
__device__ __forceinline__ u32t pk2(float a, float b){ return (u32t)f2b(a) | ((u32t)f2b(b)<<16); }
__device__ __forceinline__ bf16x8 u2b8(uint4 u){ union{uint4 a; bf16x8 b;} v; v.a=u; return v.b; }
// A-layout slot (k, m): [kb][quad][m=16][x=8] shorts
__device__ __forceinline__ int aaddr(int k, int m){ return (((k>>5)*4 + ((k>>3)&3))*16 + m)*8 + (k&7); }

// ---- dtype-agnostic load/store helpers --------------------------------------
template<bool F32> __device__ __forceinline__ float ldf(const void* p, size_t i){
    if constexpr (F32) return ((const float*)p)[i];
    else               return b2f(((const u16t*)p)[i]);
}
template<bool F32> __device__ __forceinline__ uint4 ld8p(const void* p, size_t i){
    if constexpr (F32){
        const float* f = (const float*)p + i;
        uint4 r; r.x = pk2(f[0],f[1]); r.y = pk2(f[2],f[3]);
                 r.z = pk2(f[4],f[5]); r.w = pk2(f[6],f[7]);
        return r;
    } else return *(const uint4*)((const u16t*)p + i);
}
template<bool F32> __device__ __forceinline__ void stf(void* p, size_t i, float v){
    if constexpr (F32) ((float*)p)[i] = v;
    else               ((u16t*)p)[i] = f2b(v);
}
template<bool F32> __device__ __forceinline__ float ldW_enc(const void* wih, const void* whh, int r, int k){
    if (k < CC)      return ldf<F32>(wih, (size_t)r*CC + k);
    else if (k < 72) return ldf<F32>(whh, (size_t)r*HH + (k-CC));
    else             return 0.f;
}

// dtype probe (bf16 confirmed live; kept as cheap insurance)
__device__ __forceinline__ bool inputs_are_f32(const void* bih){
    const u16t* p = (const u16t*)bih;
    int cnt = 0;
    #pragma unroll
    for (int i = 0; i < 64; ++i){
        u32t e = ((u32t)p[i] >> 7) & 0xFFu;
        cnt += (e >= 128u) ? 1 : 0;
    }
    return cnt > 0;
}

// =============================================================================
// Fused MFMA encoder+decoder, R10:
//  - x_enc staged to LDS once (no global loads in encoder loop)
//  - eoG stores delayed one step (barrier vmcnt drain ~free)
//  - P7+P1 fused algebraically: emb = relu(h @ W' + b'), W' = outW^T embW^T
//    (decoder 5 barriers/step; pred round-trip removed; outp stored by wave 3)
// A-buffers duplicate batches in M-rows 8-15 (update on all quads, 2 elems).
// eoG addr(b,h,t) = ((b*4+(h>>4))*3+(t>>5))*512+((t>>3)&3)*128+(h&15)*8+(t&7)
// =============================================================================
template<bool F32>
__global__ __launch_bounds__(256,2) void fused_g(
    const void* __restrict__ x_enc,
    const void* __restrict__ eWih, const void* __restrict__ eWhh,
    const void* __restrict__ ebih, const void* __restrict__ ebhh,
    const void* __restrict__ embW, const void* __restrict__ embb,
    const void* __restrict__ attnW, const void* __restrict__ attnb,
    const void* __restrict__ combW, const void* __restrict__ combb,
    const void* __restrict__ dWih, const void* __restrict__ dWhh,
    const void* __restrict__ dbih, const void* __restrict__ dbhh,
    const void* __restrict__ outW, const void* __restrict__ outb,
    void* __restrict__ outp, u16t* __restrict__ eoG)
{
    if (inputs_are_f32(ebih) != F32) return;

    __shared__ __align__(16) float slp[CC*10];
    __shared__ __align__(16) short Abuf2[2][1536];
    __shared__ __align__(16) u16t  xls[LL*64];     // x-sl staged, [t][b*8+i], 12 KB
    __shared__ __align__(16) char  uni[16576];

    const int tid = threadIdx.x;
    const int b0  = blockIdx.x * BT;
    const int col = tid & 15, quad = (tid >> 4) & 3, wv = tid >> 6;
    const int r0  = (quad >> 1) * 2;              // this lane's C rows r0,r0+1

    // ---------------- encoder: B-fragments + bias in registers ---------------
    bf16x8 Bf[4][3];
    float  biasg[4];
    #pragma unroll
    for (int g = 0; g < 4; ++g){
        int r = g*64 + wv*16 + col;
        biasg[g] = ldf<F32>(ebih, r) + ldf<F32>(ebhh, r);
        #pragma unroll
        for (int kb = 0; kb < 3; ++kb){
            bf16x8 v;
            #pragma unroll
            for (int x = 0; x < 8; ++x){
                int k = kb*32 + quad*8 + x;
                v[x] = (short)f2b(ldW_enc<F32>(eWih, eWhh, r, k));
            }
            Bf[g][kb] = v;
        }
    }
    for (int n = tid; n < 2*1536; n += 256) ((short*)Abuf2)[n] = 0;
    if (tid < BT*CC){ int b = tid >> 3, i = tid & 7;
        slp[i*10 + b] = ldf<F32>(x_enc, (size_t)(b0+b)*(LL*CC) + (LL-1)*CC + i); }
    __syncthreads();

    // stage x - seq_last into LDS (one-time burst; vectorized rows)
    for (int n = tid; n < BT*LL; n += 256){
        int b = n / LL, t = n - b*LL;
        uint4 p = ld8p<F32>(x_enc, ((size_t)(b0+b)*LL + t)*CC);
        uint4 q;
        q.x = pk2(lo2f(p.x) - slp[0*10+b], hi2f(p.x) - slp[1*10+b]);
        q.y = pk2(lo2f(p.y) - slp[2*10+b], hi2f(p.y) - slp[3*10+b]);
        q.z = pk2(lo2f(p.z) - slp[4*10+b], hi2f(p.z) - slp[5*10+b]);
        q.w = pk2(lo2f(p.w) - slp[6*10+b], hi2f(p.w) - slp[7*10+b]);
        *(uint4*)(xls + t*64 + b*8) = q;
    }
    __syncthreads();
    if (tid < BT*CC){ short v = (short)xls[tid];          // x(0) + dup rows
        Abuf2[0][tid] = v; Abuf2[0][tid + 64] = v; }

    const int jmy = wv*16 + col;
    const int kh  = 8 + jmy;
    const int hwbase = aaddr(kh, 0);

    u32t ebase[2];
    #pragma unroll
    for (int rr = 0; rr < 2; ++rr){
        u32t bg = (u32t)(b0 + ((quad*4 + r0 + rr) & 7));
        ebase[rr] = (bg*4u + (u32t)(jmy>>4))*1536u + (u32t)((jmy&15)*8);
    }

    float creg[2] = {0.f,0.f};
    u16t  hprev[2] = {0,0};
    u32t  offprev = 0;

    for (int t = 0; t < LL; ++t){
        __syncthreads();
        // delayed eoG store: h(t-1), now a full step old at the next barrier
        if (t > 0){
            eoG[ebase[0] + offprev] = hprev[0];
            eoG[ebase[1] + offprev] = hprev[1];
        }
        const bf16x8* AbR = (const bf16x8*)Abuf2[t & 1];
        short*        AbW = Abuf2[(t + 1) & 1];
        bf16x8 a0 = AbR[(0*4 + quad)*16 + col];
        bf16x8 a1 = AbR[(1*4 + quad)*16 + col];
        bf16x8 a2 = AbR[(2*4 + quad)*16 + col];
        f32x4 acc[4];
        #pragma unroll
        for (int g = 0; g < 4; ++g){
            f32x4 a; a[0]=biasg[g]; a[1]=biasg[g]; a[2]=biasg[g]; a[3]=biasg[g];
            a = __builtin_amdgcn_mfma_f32_16x16x32_bf16(a0, Bf[g][0], a, 0,0,0);
            a = __builtin_amdgcn_mfma_f32_16x16x32_bf16(a1, Bf[g][1], a, 0,0,0);
            a = __builtin_amdgcn_mfma_f32_16x16x32_bf16(a2, Bf[g][2], a, 0,0,0);
            acc[g] = a;
        }
        u32t off = (u32t)((t>>5)*512 + ((t>>3)&3)*128 + (t&7));
        #pragma unroll
        for (int rr = 0; rr < 2; ++rr){
            int r = r0 + rr;
            int b = (quad*4 + r) & 7;
            float c = sigm(acc[1][r])*creg[rr] + sigm(acc[0][r])*tanh2(acc[2][r]);
            float h = sigm(acc[3][r])*tanh2(c);
            creg[rr] = c; hprev[rr] = f2b(h);
            AbW[hwbase + b*8]     = (short)hprev[rr];
            AbW[hwbase + (b+8)*8] = (short)hprev[rr];
        }
        offprev = off;
        if (tid < BT*CC && t < LL-1){
            short v = (short)xls[(t+1)*64 + tid];
            AbW[tid] = v; AbW[tid + 64] = v;
        }
    }
    // final eoG store (h(LL-1))
    eoG[ebase[0] + offprev] = hprev[0];
    eoG[ebase[1] + offprev] = hprev[1];

    // ---------------- decoder weight fragments (registers) ------------------
    bf16x8 Bd[4][4];
    #pragma unroll
    for (int g = 0; g < 4; ++g){
        int r = g*64 + wv*16 + col;
        Bd[g][0] = u2b8(ld8p<F32>(dWih, (size_t)r*HH + quad*8));
        Bd[g][1] = u2b8(ld8p<F32>(dWih, (size_t)r*HH + 32 + quad*8));
        Bd[g][2] = u2b8(ld8p<F32>(dWhh, (size_t)r*HH + quad*8));
        Bd[g][3] = u2b8(ld8p<F32>(dWhh, (size_t)r*HH + 32 + quad*8));
    }
    bf16x8 Ba[2][4];
    #pragma unroll
    for (int kb = 0; kb < 4; ++kb)
        Ba[0][kb] = u2b8(ld8p<F32>(attnW, (size_t)(wv*16+col)*128 + kb*32 + quad*8));
    if (wv < 2){
        #pragma unroll
        for (int kb = 0; kb < 4; ++kb)
            Ba[1][kb] = u2b8(ld8p<F32>(attnW, (size_t)((4+wv)*16+col)*128 + kb*32 + quad*8));
    } else {
        #pragma unroll
        for (int kb = 0; kb < 4; ++kb) Ba[1][kb] = Ba[0][kb];
    }
    bf16x8 Bc[4];
    #pragma unroll
    for (int kb = 0; kb < 4; ++kb)
        Bc[kb] = u2b8(ld8p<F32>(combW, (size_t)(wv*16+col)*128 + kb*32 + quad*8));
    bf16x8 zz = {0,0,0,0,0,0,0,0};
    bf16x8 oBf0 = zz, oBf1 = zz;           // outW B-frags (n=col<8 real)
    if (col < CC){
        oBf0 = u2b8(ld8p<F32>(outW, (size_t)col*HH + quad*8));
        oBf1 = u2b8(ld8p<F32>(outW, (size_t)col*HH + 32 + quad*8));
    }
    // fused pred->emb weight: W'[j][n] = sum_i outW[i][j]*embW[n][i]
    bf16x8 wpf[2];
    float  bprime;
    u16t   e0bu;
    {
        int n = wv*16 + col;
        #pragma unroll
        for (int kb = 0; kb < 2; ++kb){
            bf16x8 v;
            #pragma unroll
            for (int x = 0; x < 8; ++x){
                int j = kb*32 + quad*8 + x;
                float s = 0.f;
                #pragma unroll
                for (int i = 0; i < CC; ++i)
                    s += ldf<F32>(outW, (size_t)i*HH + j) * ldf<F32>(embW, (size_t)n*CC + i);
                v[x] = (short)f2b(s);
            }
            wpf[kb] = v;
        }
        float bp = ldf<F32>(embb, n);
        #pragma unroll
        for (int i = 0; i < CC; ++i)
            bp += ldf<F32>(outb, i) * ldf<F32>(embW, (size_t)n*CC + i);
        bprime = bp;
        e0bu = f2b(fmaxf(ldf<F32>(embb, n), 0.f));   // emb at t=0 (pred=0)
    }

    // ---------------- decoder LDS views + init ----------------
    float* decB  = (float*)(uni + 0);      // 256 f
    float* attnB = (float*)(uni + 1024);   // 96 f
    float* combB = (float*)(uni + 1408);   // 64 f
    float* outB  = (float*)(uni + 1664);   // 8 f
    float* Lg    = (float*)(uni + 1728);   // [l][8b] logits (3072 B)
    u16t*  awB   = (u16t*)(uni + 4800);    // aw bf16 [b][96] (1536 B)
    u16t*  Ae    = (u16t*)(uni + 6336);    // emb A-buf
    u16t*  Ah0   = (u16t*)(uni + 8384);    // h A-buf ping
    u16t*  Ah1   = (u16t*)(uni + 10432);   // h A-buf pong
    u16t*  Actx  = (u16t*)(uni + 12480);   // ctx A-buf
    u16t*  Acmb  = (u16t*)(uni + 14528);   // comb A-buf

    #pragma unroll
    for (int rr = 0; rr < 2; ++rr){
        int b = (quad*4 + r0 + rr) & 7;
        Ah0[aaddr(jmy, b)]   = hprev[rr];
        Ah0[aaddr(jmy, b+8)] = hprev[rr];
    }
    decB[tid] = ldf<F32>(dbih, tid) + ldf<F32>(dbhh, tid);
    if (tid < LL) attnB[tid] = ldf<F32>(attnb, tid);
    if (tid < HH) combB[tid] = ldf<F32>(combb, tid);
    if (tid < CC) outB[tid]  = ldf<F32>(outb, tid);
    __syncthreads();

    // eoG fragments for this wave's 2 batches -> registers
    const u16t* ebp = eoG + (size_t)(b0 + wv*2) * 6144;
    uint4 eF0[12], eF1[12];
    #pragma unroll
    for (int f = 0; f < 12; ++f) eF0[f] = *(const uint4*)(ebp + f*512 + quad*128 + col*8);
    #pragma unroll
    for (int f = 0; f < 12; ++f) eF1[f] = *(const uint4*)(ebp + 6144 + f*512 + quad*128 + col*8);

    const int lgS = tid & 31, bS = tid >> 5;
    const bf16x8* AeV   = (const bf16x8*)Ae;
    const bf16x8* ActxV = (const bf16x8*)Actx;
    const bf16x8* AcmbV = (const bf16x8*)Acmb;

    for (int t = 0; t < TT; ++t){
        u16t* AhR = (t & 1) ? Ah1 : Ah0;
        u16t* AhW = (t & 1) ? Ah0 : Ah1;
        const bf16x8* AhV = (const bf16x8*)AhR;

        // Pe: emb = relu(h_{t-1} @ W' + b') via 2 MFMA -> Ae (all rows);
        //     wave 3 also computes pred_{t-1} = h_{t-1}@outW^T+outb -> outp
        {
            bf16x8 h0 = AhV[(0*4+quad)*16 + col];
            bf16x8 h1 = AhV[(1*4+quad)*16 + col];
            if (t == 0){
                #pragma unroll
                for (int r = 0; r < 4; ++r)
                    Ae[aaddr(wv*16+col, quad*4 + r)] = e0bu;
            } else {
                f32x4 a; a[0]=bprime; a[1]=bprime; a[2]=bprime; a[3]=bprime;
                a = __builtin_amdgcn_mfma_f32_16x16x32_bf16(h0, wpf[0], a, 0,0,0);
                a = __builtin_amdgcn_mfma_f32_16x16x32_bf16(h1, wpf[1], a, 0,0,0);
                #pragma unroll
                for (int r = 0; r < 4; ++r)
                    Ae[aaddr(wv*16+col, quad*4 + r)] = f2b(fmaxf(a[r], 0.f));
            }
            if (wv == 3 && t > 0){
                float ob = outB[col & 7];
                f32x4 a; a[0]=ob; a[1]=ob; a[2]=ob; a[3]=ob;
                a = __builtin_amdgcn_mfma_f32_16x16x32_bf16(h0, oBf0, a, 0,0,0);
                a = __builtin_amdgcn_mfma_f32_16x16x32_bf16(h1, oBf1, a, 0,0,0);
                if (col < CC){
                    #pragma unroll
                    for (int r = 0; r < 4; ++r){
                        int m = quad*4 + r;
                        if (m < 8)
                            stf<F32>(outp, ((size_t)(b0+m)*TT + (t-1))*CC + col,
                                     a[r] + slp[col*10 + m]);
                    }
                }
            }
        }
        __syncthreads();

        // P2a: attention logits via MFMA -> Lg (rows 0-7 real)
        {
            bf16x8 ae0 = AeV[(0*4+quad)*16 + col], ae1 = AeV[(1*4+quad)*16 + col];
            bf16x8 ah0 = AhV[(0*4+quad)*16 + col], ah1 = AhV[(1*4+quad)*16 + col];
            const int ns = (wv < 2) ? 2 : 1;
            for (int s = 0; s < ns; ++s){
                int lt = (s == 0) ? wv : 4+wv;
                float bz = attnB[lt*16 + col];
                f32x4 a; a[0]=bz; a[1]=bz; a[2]=bz; a[3]=bz;
                a = __builtin_amdgcn_mfma_f32_16x16x32_bf16(ae0, Ba[s][0], a, 0,0,0);
                a = __builtin_amdgcn_mfma_f32_16x16x32_bf16(ae1, Ba[s][1], a, 0,0,0);
                a = __builtin_amdgcn_mfma_f32_16x16x32_bf16(ah0, Ba[s][2], a, 0,0,0);
                a = __builtin_amdgcn_mfma_f32_16x16x32_bf16(ah1, Ba[s][3], a, 0,0,0);
                if (quad < 2)
                    *(float4*)&Lg[(lt*16+col)*8 + quad*4] = make_float4(a[0],a[1],a[2],a[3]);
            }
        }
        __syncthreads();

        // P2b: softmax per batch -> awB (bf16, A-broadcast rows)
        {
            int l = lgS*3;
            float ev0 = Lg[l*8 + bS], ev1 = Lg[(l+1)*8 + bS], ev2 = Lg[(l+2)*8 + bS];
            float mx = fmaxf(ev0, fmaxf(ev1, ev2));
            #pragma unroll
            for (int m = 16; m >= 1; m >>= 1) mx = fmaxf(mx, __shfl_xor(mx, m, 32));
            float e0 = __expf(ev0 - mx), e1 = __expf(ev1 - mx), e2 = __expf(ev2 - mx);
            float sm = e0 + e1 + e2;
            #pragma unroll
            for (int m = 16; m >= 1; m >>= 1) sm += __shfl_xor(sm, m, 32);
            float inv = rcpf(sm);
            awB[bS*96 + l]     = f2b(e0*inv);
            awB[bS*96 + l + 1] = f2b(e1*inv);
            awB[bS*96 + l + 2] = f2b(e2*inv);
        }
        // P3: ctx via MFMA (A = aw broadcast, B = register eo frags); intra-wave
        // RAW on awB (same 32-lane group), no barrier.
        {
            const u16t* ap0 = awB + (wv*2)*96;
            bf16x8 f0 = *(const bf16x8*)(ap0 + quad*8);
            bf16x8 f1 = *(const bf16x8*)(ap0 + 32 + quad*8);
            bf16x8 f2 = *(const bf16x8*)(ap0 + 64 + quad*8);
            #pragma unroll
            for (int nt = 0; nt < 4; ++nt){
                f32x4 a; a[0]=0.f; a[1]=0.f; a[2]=0.f; a[3]=0.f;
                a = __builtin_amdgcn_mfma_f32_16x16x32_bf16(f0, u2b8(eF0[nt*3+0]), a, 0,0,0);
                a = __builtin_amdgcn_mfma_f32_16x16x32_bf16(f1, u2b8(eF0[nt*3+1]), a, 0,0,0);
                a = __builtin_amdgcn_mfma_f32_16x16x32_bf16(f2, u2b8(eF0[nt*3+2]), a, 0,0,0);
                if (quad == 0){
                    u16t v = f2b(a[0]);
                    Actx[aaddr(nt*16+col, wv*2)]   = v;
                    Actx[aaddr(nt*16+col, wv*2+8)] = v;
                }
            }
            const u16t* ap1 = awB + (wv*2+1)*96;
            bf16x8 g0 = *(const bf16x8*)(ap1 + quad*8);
            bf16x8 g1 = *(const bf16x8*)(ap1 + 32 + quad*8);
            bf16x8 g2 = *(const bf16x8*)(ap1 + 64 + quad*8);
            #pragma unroll
            for (int nt = 0; nt < 4; ++nt){
                f32x4 a; a[0]=0.f; a[1]=0.f; a[2]=0.f; a[3]=0.f;
                a = __builtin_amdgcn_mfma_f32_16x16x32_bf16(g0, u2b8(eF1[nt*3+0]), a, 0,0,0);
                a = __builtin_amdgcn_mfma_f32_16x16x32_bf16(g1, u2b8(eF1[nt*3+1]), a, 0,0,0);
                a = __builtin_amdgcn_mfma_f32_16x16x32_bf16(g2, u2b8(eF1[nt*3+2]), a, 0,0,0);
                if (quad == 0){
                    u16t v = f2b(a[0]);
                    Actx[aaddr(nt*16+col, wv*2+1)] = v;
                    Actx[aaddr(nt*16+col, wv*2+9)] = v;
                }
            }
        }
        __syncthreads();

        // P4: comb = [emb|ctx] @ combW^T + b via MFMA -> Acmb (all rows)
        {
            bf16x8 ae0 = AeV[(0*4+quad)*16 + col],   ae1 = AeV[(1*4+quad)*16 + col];
            bf16x8 ax0 = ActxV[(0*4+quad)*16 + col], ax1 = ActxV[(1*4+quad)*16 + col];
            float bz = combB[wv*16 + col];
            f32x4 a; a[0]=bz; a[1]=bz; a[2]=bz; a[3]=bz;
            a = __builtin_amdgcn_mfma_f32_16x16x32_bf16(ae0, Bc[0], a, 0,0,0);
            a = __builtin_amdgcn_mfma_f32_16x16x32_bf16(ae1, Bc[1], a, 0,0,0);
            a = __builtin_amdgcn_mfma_f32_16x16x32_bf16(ax0, Bc[2], a, 0,0,0);
            a = __builtin_amdgcn_mfma_f32_16x16x32_bf16(ax1, Bc[3], a, 0,0,0);
            #pragma unroll
            for (int r = 0; r < 4; ++r)
                Acmb[aaddr(wv*16+col, quad*4 + r)] = f2b(a[r]);
        }
        __syncthreads();

        // P5: dec LSTM gates via MFMA; all-lane 2-elem update; h -> AhW (+dup)
        {
            bf16x8 ac0 = AcmbV[(0*4+quad)*16 + col], ac1 = AcmbV[(1*4+quad)*16 + col];
            bf16x8 ah0 = AhV[(0*4+quad)*16 + col],   ah1 = AhV[(1*4+quad)*16 + col];
            f32x4 g4[4];
            #pragma unroll
            for (int g = 0; g < 4; ++g){
                float bz = decB[g*64 + wv*16 + col];
                f32x4 a; a[0]=bz; a[1]=bz; a[2]=bz; a[3]=bz;
                a = __builtin_amdgcn_mfma_f32_16x16x32_bf16(ac0, Bd[g][0], a, 0,0,0);
                a = __builtin_amdgcn_mfma_f32_16x16x32_bf16(ac1, Bd[g][1], a, 0,0,0);
                a = __builtin_amdgcn_mfma_f32_16x16x32_bf16(ah0, Bd[g][2], a, 0,0,0);
                a = __builtin_amdgcn_mfma_f32_16x16x32_bf16(ah1, Bd[g][3], a, 0,0,0);
                g4[g] = a;
            }
            #pragma unroll
            for (int rr = 0; rr < 2; ++rr){
                int r = r0 + rr;
                int b = (quad*4 + r) & 7;
                float c = sigm(g4[1][r])*creg[rr] + sigm(g4[0][r])*tanh2(g4[2][r]);
                float h = sigm(g4[3][r])*tanh2(c);
                creg[rr] = c;
                u16t hv = f2b(h);
                AhW[aaddr(jmy, b)]   = hv;
                AhW[aaddr(jmy, b+8)] = hv;
            }
        }
        __syncthreads();
    }

    // epilogue: pred_{TT-1} from final h (in Ah0 after t=23's P5) -> outp
    if (wv == 3){
        const bf16x8* AhV = (const bf16x8*)Ah0;
        bf16x8 h0 = AhV[(0*4+quad)*16 + col];
        bf16x8 h1 = AhV[(1*4+quad)*16 + col];
        float ob = outB[col & 7];
        f32x4 a; a[0]=ob; a[1]=ob; a[2]=ob; a[3]=ob;
        a = __builtin_amdgcn_mfma_f32_16x16x32_bf16(h0, oBf0, a, 0,0,0);
        a = __builtin_amdgcn_mfma_f32_16x16x32_bf16(h1, oBf1, a, 0,0,0);
        if (col < CC){
            #pragma unroll
            for (int r = 0; r < 4; ++r){
                int m = quad*4 + r;
                if (m < 8)
                    stf<F32>(outp, ((size_t)(b0+m)*TT + (TT-1))*CC + col,
                             a[r] + slp[col*10 + m]);
            }
        }
    }
}

// --------------------------------------------------------------- launch -----
extern "C" void kernel_launch(void* const* d_in, const int* in_sizes, int n_in,
                              void* d_out, int out_size, void* d_ws, size_t ws_size,
                              hipStream_t stream)
{
    (void)in_sizes; (void)n_in; (void)out_size; (void)ws_size;
    fused_g<false><<<NB, 256, 0, stream>>>(
        d_in[0],
        d_in[4],  d_in[5],  d_in[6],  d_in[7],
        d_in[8],  d_in[9],  d_in[10], d_in[11],
        d_in[12], d_in[13], d_in[14], d_in[15],
        d_in[16], d_in[17], d_in[18], d_in[19],
        d_out, (u16t*)d_ws);
    fused_g<true><<<NB, 256, 0, stream>>>(
        d_in[0],
        d_in[4],  d_in[5],  d_in[6],  d_in[7],
        d_in[8],  d_in[9],  d_in[10], d_in[11],
        d_in[12], d_in[13], d_in[14], d_in[15],
        d_in[16], d_in[17], d_in[18], d_in[19],
        d_out, (u16t*)d_ws);
}